// Round 3
// baseline (70.352 us; speedup 1.0000x reference)
//
#include <hip/hip_runtime.h>

#define VOCAB 50257
#define EMBED 128
#define NTOK  (64 * 4096)

typedef float f32x4 __attribute__((ext_vector_type(4)));

// Pass 1: Wt[v][e] = W[e][v] + bias[e]   (LDS-tiled transpose, bias folded in)
// grid.x = ceil(VOCAB/64), block = 256
__global__ void transpose_bias_kernel(const float* __restrict__ W,
                                      const float* __restrict__ bias,
                                      float* __restrict__ Wt) {
    __shared__ float tile[64][EMBED + 1];  // +1 pad breaks bank conflicts
    const int t  = threadIdx.x;
    const int v0 = blockIdx.x * 64;

    // Load W[e][v0+c] -> tile[c][e]; coalesced in v (64 consecutive lanes/row).
    // NT loads: W is read exactly once, don't pollute L2/L3 (Wt wants residency).
#pragma unroll
    for (int it = 0; it < 32; ++it) {
        const int e = (t >> 6) + it * 4;   // 4 e-rows per iteration
        const int c = t & 63;
        const int v = v0 + c;
        float val = 0.0f;
        if (v < VOCAB) val = __builtin_nontemporal_load(&W[e * VOCAB + v]);
        tile[c][e] = val;                  // stride 129 floats -> conflict-free
    }
    __syncthreads();

    const float bval = bias[t & (EMBED - 1)];
    // Store Wt[v][e]; coalesced in e. Cached stores: Wt should stay in L2/L3.
#pragma unroll
    for (int it = 0; it < 32; ++it) {
        const int c = (t >> 7) + it * 2;   // 2 v-columns per iteration
        const int e = t & (EMBED - 1);
        const int v = v0 + c;
        if (v < VOCAB) Wt[v * EMBED + e] = tile[c][e] + bval;
    }
}

// Pass 2: out[token][:] = Wt[x[token]][:]  — coalesced 512B row copies.
// 32 lanes per token (f32x4 each); 4 (token,e4) pairs per thread for ILP.
// NT stores: out is write-only -> don't evict Wt from L2/L3.
__global__ void gather_kernel(const int* __restrict__ x,
                              const f32x4* __restrict__ Wt,
                              f32x4* __restrict__ out) {
    const int gid    = blockIdx.x * blockDim.x + threadIdx.x;
    const int stride = gridDim.x * blockDim.x;   // total threads

    int g[4], idx[4];
#pragma unroll
    for (int k = 0; k < 4; ++k) {
        g[k]   = gid + k * stride;
        idx[k] = x[g[k] >> 5];               // broadcast within 32-lane group
    }
    f32x4 v[4];
#pragma unroll
    for (int k = 0; k < 4; ++k)
        v[k] = Wt[idx[k] * 32 + (g[k] & 31)];
#pragma unroll
    for (int k = 0; k < 4; ++k)
        __builtin_nontemporal_store(v[k], &out[g[k]]);  // out offset == g[k]
}

// Fallback if workspace too small: strided column gather (W stays row-major).
__global__ void direct_kernel(const int* __restrict__ x,
                              const float* __restrict__ W,
                              const float* __restrict__ bias,
                              f32x4* __restrict__ out) {
    const int gid   = blockIdx.x * blockDim.x + threadIdx.x;
    const int token = gid >> 5;
    const int e4    = gid & 31;
    const int idx   = x[token];
    const int e     = e4 * 4;
    f32x4 r;
    r.x = W[(e + 0) * VOCAB + idx] + bias[e + 0];
    r.y = W[(e + 1) * VOCAB + idx] + bias[e + 1];
    r.z = W[(e + 2) * VOCAB + idx] + bias[e + 2];
    r.w = W[(e + 3) * VOCAB + idx] + bias[e + 3];
    out[token * 32 + e4] = r;
}

extern "C" void kernel_launch(void* const* d_in, const int* in_sizes, int n_in,
                              void* d_out, int out_size, void* d_ws, size_t ws_size,
                              hipStream_t stream) {
    const int*   x    = (const int*)d_in[0];
    const float* W    = (const float*)d_in[1];
    const float* bias = (const float*)d_in[2];

    const size_t wt_bytes = (size_t)VOCAB * EMBED * sizeof(float);

    // total f32x4 elements = NTOK*32 = 8,388,608; 4 per thread
    const int total_thr = NTOK * 32 / 4;       // 2,097,152
    const int gblocks   = total_thr / 256;     // 8192

    if (ws_size >= wt_bytes) {
        float* Wt = (float*)d_ws;
        const int tblocks = (VOCAB + 63) / 64;  // 786
        transpose_bias_kernel<<<tblocks, 256, 0, stream>>>(W, bias, Wt);
        gather_kernel<<<gblocks, 256, 0, stream>>>(x, (const f32x4*)Wt,
                                                   (f32x4*)d_out);
    } else {
        const int dblocks = (NTOK * 32) / 256;
        direct_kernel<<<dblocks, 256, 0, stream>>>(x, W, bias, (f32x4*)d_out);
    }
}

// Round 4
// 61.572 us; speedup vs baseline: 1.1426x; 1.1426x over previous
//
#include <hip/hip_runtime.h>

#define VOCAB 50257
#define EMBED 128
#define NTOK  (64 * 4096)

typedef float f32x4 __attribute__((ext_vector_type(4)));

// Pass 1: Wt[v][e] = W[e][v] + bias[e]   (LDS-tiled transpose, bias folded in)
// Tile: 64 v-cols x 128 e-rows per block. 256 threads. All 16B accesses.
__global__ void transpose_bias_kernel(const float* __restrict__ W,
                                      const float* __restrict__ bias,
                                      float* __restrict__ Wt) {
    __shared__ float tile[64][EMBED + 1];  // +1 pad: conflict-free scatter
    const int t  = threadIdx.x;
    const int v0 = blockIdx.x * 64;
    const bool full = (v0 + 64 <= VOCAB);

    // Phase 1: load W[e][v0 + 4*(t&15) .. +3] as f32x4; 16 e-rows per iter.
    if (full) {
#pragma unroll
        for (int it = 0; it < 8; ++it) {
            const int e  = (t >> 4) + it * 16;
            const int c4 = (t & 15) * 4;
            f32x4 val = *(const f32x4*)&W[e * VOCAB + v0 + c4];
            tile[c4 + 0][e] = val.x;
            tile[c4 + 1][e] = val.y;
            tile[c4 + 2][e] = val.z;
            tile[c4 + 3][e] = val.w;
        }
    } else {
        // Tail block (v0=50240..50256): scalar guarded loads.
#pragma unroll
        for (int it = 0; it < 32; ++it) {
            const int e = (t >> 6) + it * 4;
            const int c = t & 63;
            const int v = v0 + c;
            tile[c][e] = (v < VOCAB) ? W[e * VOCAB + v] : 0.0f;
        }
    }
    __syncthreads();

    // Phase 2: store Wt[v][e0..e0+3] + bias, f32x4; 8 v-rows per iter.
    const int e0 = (t & 31) * 4;
    const f32x4 b4 = *(const f32x4*)&bias[e0];
#pragma unroll
    for (int it = 0; it < 8; ++it) {
        const int c = (t >> 5) + it * 8;
        const int v = v0 + c;
        if (v < VOCAB) {
            f32x4 r;
            r.x = tile[c][e0 + 0] + b4.x;
            r.y = tile[c][e0 + 1] + b4.y;
            r.z = tile[c][e0 + 2] + b4.z;
            r.w = tile[c][e0 + 3] + b4.w;
            *(f32x4*)&Wt[v * EMBED + e0] = r;
        }
    }
}

// Pass 2: out[token][:] = Wt[x[token]][:] — coalesced 512B row copies.
// 32 lanes per token (f32x4 each); 4 independent (token,e4) pairs per thread
// for memory-level parallelism. Plain cached stores (NT regressed: R3).
__global__ void gather_kernel(const int* __restrict__ x,
                              const f32x4* __restrict__ Wt,
                              f32x4* __restrict__ out) {
    const int gid    = blockIdx.x * blockDim.x + threadIdx.x;
    const int stride = gridDim.x * blockDim.x;

    int g[4], idx[4];
#pragma unroll
    for (int k = 0; k < 4; ++k) {
        g[k]   = gid + k * stride;
        idx[k] = x[g[k] >> 5];               // broadcast within 32-lane group
    }
    f32x4 v[4];
#pragma unroll
    for (int k = 0; k < 4; ++k)
        v[k] = Wt[idx[k] * 32 + (g[k] & 31)];
#pragma unroll
    for (int k = 0; k < 4; ++k)
        out[g[k]] = v[k];
}

// Fallback if workspace too small: strided column gather.
__global__ void direct_kernel(const int* __restrict__ x,
                              const float* __restrict__ W,
                              const float* __restrict__ bias,
                              f32x4* __restrict__ out) {
    const int gid   = blockIdx.x * blockDim.x + threadIdx.x;
    const int token = gid >> 5;
    const int e4    = gid & 31;
    const int idx   = x[token];
    const int e     = e4 * 4;
    f32x4 r;
    r.x = W[(e + 0) * VOCAB + idx] + bias[e + 0];
    r.y = W[(e + 1) * VOCAB + idx] + bias[e + 1];
    r.z = W[(e + 2) * VOCAB + idx] + bias[e + 2];
    r.w = W[(e + 3) * VOCAB + idx] + bias[e + 3];
    out[token * 32 + e4] = r;
}

extern "C" void kernel_launch(void* const* d_in, const int* in_sizes, int n_in,
                              void* d_out, int out_size, void* d_ws, size_t ws_size,
                              hipStream_t stream) {
    const int*   x    = (const int*)d_in[0];
    const float* W    = (const float*)d_in[1];
    const float* bias = (const float*)d_in[2];

    const size_t wt_bytes = (size_t)VOCAB * EMBED * sizeof(float);

    // total f32x4 elements = NTOK*32 = 8,388,608; 4 per thread
    const int total_thr = NTOK * 32 / 4;       // 2,097,152
    const int gblocks   = total_thr / 256;     // 8192

    if (ws_size >= wt_bytes) {
        float* Wt = (float*)d_ws;
        const int tblocks = (VOCAB + 63) / 64;  // 786
        transpose_bias_kernel<<<tblocks, 256, 0, stream>>>(W, bias, Wt);
        gather_kernel<<<gblocks, 256, 0, stream>>>(x, (const f32x4*)Wt,
                                                   (f32x4*)d_out);
    } else {
        const int dblocks = (NTOK * 32) / 256;
        direct_kernel<<<dblocks, 256, 0, stream>>>(x, W, bias, (f32x4*)d_out);
    }
}

// Round 5
// 47.750 us; speedup vs baseline: 1.4733x; 1.2895x over previous
//
#include <hip/hip_runtime.h>

#define VOCAB 50257
#define EMBED 128
#define NTOK  (64 * 4096)

typedef float    f32x4 __attribute__((ext_vector_type(4)));
typedef _Float16 f16x8 __attribute__((ext_vector_type(8)));

// Pass 1: Wt_h[v][e] = (half)W[e][v]  — LDS-tiled transpose, fp16 output.
// Tile: 64 v x 64 e. grid = (786, 2), block = 256.
__global__ void transpose_h_kernel(const float* __restrict__ W,
                                   _Float16* __restrict__ Wt) {
    __shared__ float tile[64][65];   // [v_loc][e_loc], +1 pad
    const int t  = threadIdx.x;
    const int v0 = blockIdx.x * 64;
    const int e0 = blockIdx.y * 64;
    const bool full = (v0 + 64 <= VOCAB);

    // Phase 1: load W[e0+e_loc][v0 + 4*(t&15) .. +3] as f32x4.
    if (full) {
#pragma unroll
        for (int it = 0; it < 4; ++it) {
            const int e_loc = (t >> 4) + it * 16;
            const int c4    = (t & 15) * 4;
            f32x4 val = *(const f32x4*)&W[(size_t)(e0 + e_loc) * VOCAB + v0 + c4];
            tile[c4 + 0][e_loc] = val.x;
            tile[c4 + 1][e_loc] = val.y;
            tile[c4 + 2][e_loc] = val.z;
            tile[c4 + 3][e_loc] = val.w;
        }
    } else {
        // Tail v-block (v0 = 50240, 17 valid): guarded scalar loads.
#pragma unroll
        for (int it = 0; it < 16; ++it) {
            const int e_loc = (t >> 6) + it * 4;
            const int c     = t & 63;
            const int v     = v0 + c;
            tile[c][e_loc] = (v < VOCAB) ? W[(size_t)(e0 + e_loc) * VOCAB + v]
                                         : 0.0f;
        }
    }
    __syncthreads();

    // Phase 2: write Wt_h[v][e0 + 8*(t&7) .. +7] as f16x8 (16 B).
#pragma unroll
    for (int it = 0; it < 2; ++it) {
        const int v_loc = (t >> 3) + it * 32;
        const int eo    = (t & 7) * 8;
        const int v     = v0 + v_loc;
        if (v < VOCAB) {
            f16x8 h;
#pragma unroll
            for (int j = 0; j < 8; ++j)
                h[j] = (_Float16)tile[v_loc][eo + j];
            *(f16x8*)&Wt[(size_t)v * EMBED + e0 + eo] = h;
        }
    }
}

// Pass 2: out[token][:] = (float)Wt_h[x[token]][:] + bias  — 16 lanes/token,
// f16x8 (16 B) read + 2x f32x4 (32 B) write per lane; 2 tokens per thread.
__global__ void gather_h_kernel(const int* __restrict__ x,
                                const f16x8* __restrict__ Wt,
                                const float* __restrict__ bias,
                                f32x4* __restrict__ out) {
    const int gid    = blockIdx.x * blockDim.x + threadIdx.x;
    const int stride = gridDim.x * blockDim.x;
    const int oct    = gid & 15;                 // same for both slices
    const f32x4 blo  = *(const f32x4*)&bias[oct * 8];
    const f32x4 bhi  = *(const f32x4*)&bias[oct * 8 + 4];

    const int t0 = gid >> 4;
    const int t1 = (gid + stride) >> 4;
    const int i0 = x[t0];
    const int i1 = x[t1];
    const f16x8 h0 = Wt[i0 * 16 + oct];
    const f16x8 h1 = Wt[i1 * 16 + oct];

    f32x4 lo, hi;
    lo.x = (float)h0[0] + blo.x; lo.y = (float)h0[1] + blo.y;
    lo.z = (float)h0[2] + blo.z; lo.w = (float)h0[3] + blo.w;
    hi.x = (float)h0[4] + bhi.x; hi.y = (float)h0[5] + bhi.y;
    hi.z = (float)h0[6] + bhi.z; hi.w = (float)h0[7] + bhi.w;
    f32x4* o0 = out + (size_t)t0 * 32 + oct * 2;
    o0[0] = lo; o0[1] = hi;

    lo.x = (float)h1[0] + blo.x; lo.y = (float)h1[1] + blo.y;
    lo.z = (float)h1[2] + blo.z; lo.w = (float)h1[3] + blo.w;
    hi.x = (float)h1[4] + bhi.x; hi.y = (float)h1[5] + bhi.y;
    hi.z = (float)h1[6] + bhi.z; hi.w = (float)h1[7] + bhi.w;
    f32x4* o1 = out + (size_t)t1 * 32 + oct * 2;
    o1[0] = lo; o1[1] = hi;
}

// Fallback (ws too small): exact fp32 strided column gather.
__global__ void direct_kernel(const int* __restrict__ x,
                              const float* __restrict__ W,
                              const float* __restrict__ bias,
                              f32x4* __restrict__ out) {
    const int gid   = blockIdx.x * blockDim.x + threadIdx.x;
    const int token = gid >> 5;
    const int e4    = gid & 31;
    const int idx   = x[token];
    const int e     = e4 * 4;
    f32x4 r;
    r.x = W[(size_t)(e + 0) * VOCAB + idx] + bias[e + 0];
    r.y = W[(size_t)(e + 1) * VOCAB + idx] + bias[e + 1];
    r.z = W[(size_t)(e + 2) * VOCAB + idx] + bias[e + 2];
    r.w = W[(size_t)(e + 3) * VOCAB + idx] + bias[e + 3];
    out[(size_t)token * 32 + e4] = r;
}

extern "C" void kernel_launch(void* const* d_in, const int* in_sizes, int n_in,
                              void* d_out, int out_size, void* d_ws, size_t ws_size,
                              hipStream_t stream) {
    const int*   x    = (const int*)d_in[0];
    const float* W    = (const float*)d_in[1];
    const float* bias = (const float*)d_in[2];

    const size_t wt_bytes = (size_t)VOCAB * EMBED * sizeof(_Float16); // 12.9 MB

    if (ws_size >= wt_bytes) {
        _Float16* Wt = (_Float16*)d_ws;
        dim3 tgrid((VOCAB + 63) / 64, 2);   // 786 x 2 = 1572 blocks
        transpose_h_kernel<<<tgrid, 256, 0, stream>>>(W, Wt);

        // slices = NTOK*16 = 4,194,304; 2 per thread -> 2,097,152 threads
        const int gblocks = (NTOK * 16 / 2) / 256;   // 8192
        gather_h_kernel<<<gblocks, 256, 0, stream>>>(x, (const f16x8*)Wt,
                                                     bias, (f32x4*)d_out);
    } else {
        const int dblocks = (NTOK * 32) / 256;
        direct_kernel<<<dblocks, 256, 0, stream>>>(x, W, bias, (f32x4*)d_out);
    }
}

// Round 6
// 46.937 us; speedup vs baseline: 1.4989x; 1.0173x over previous
//
#include <hip/hip_runtime.h>

#define VOCAB 50257
#define EMBED 128
#define NTOK  (64 * 4096)

typedef float    f32x4 __attribute__((ext_vector_type(4)));
typedef _Float16 f16x4 __attribute__((ext_vector_type(4)));
typedef _Float16 f16x8 __attribute__((ext_vector_type(8)));

// Pass 1: Wt_h[v][e] = (half)(W[e][v] + bias[e]) — LDS-tiled transpose,
// bias folded, fp16 output. Tile 64v x 64e. grid=(786,2), block=256.
__global__ void transpose_h_kernel(const float* __restrict__ W,
                                   const float* __restrict__ bias,
                                   _Float16* __restrict__ Wt) {
    __shared__ float tile[64][65];   // [v_loc][e_loc], +1 pad
    const int t  = threadIdx.x;
    const int v0 = blockIdx.x * 64;
    const int e0 = blockIdx.y * 64;
    const bool full = (v0 + 64 <= VOCAB);

    // Phase 1: load W[e0+e_loc][v0 + 4*(t&15) .. +3] as f32x4.
    if (full) {
#pragma unroll
        for (int it = 0; it < 4; ++it) {
            const int e_loc = (t >> 4) + it * 16;
            const int c4    = (t & 15) * 4;
            f32x4 val = *(const f32x4*)&W[(size_t)(e0 + e_loc) * VOCAB + v0 + c4];
            tile[c4 + 0][e_loc] = val.x;
            tile[c4 + 1][e_loc] = val.y;
            tile[c4 + 2][e_loc] = val.z;
            tile[c4 + 3][e_loc] = val.w;
        }
    } else {
        // Tail v-block (v0 = 50240, 17 valid): guarded scalar loads.
#pragma unroll
        for (int it = 0; it < 16; ++it) {
            const int e_loc = (t >> 6) + it * 4;
            const int c     = t & 63;
            const int v     = v0 + c;
            tile[c][e_loc] = (v < VOCAB) ? W[(size_t)(e0 + e_loc) * VOCAB + v]
                                         : 0.0f;
        }
    }
    __syncthreads();

    // Phase 2: Wt_h[v][e0 + 8*(t&7) .. +7] = half(tile + bias), f16x8 (16 B).
    const int eo = (t & 7) * 8;
    const f32x4 ba = *(const f32x4*)&bias[e0 + eo];
    const f32x4 bb = *(const f32x4*)&bias[e0 + eo + 4];
#pragma unroll
    for (int it = 0; it < 2; ++it) {
        const int v_loc = (t >> 3) + it * 32;
        const int v     = v0 + v_loc;
        if (v < VOCAB) {
            f16x8 h;
            h[0] = (_Float16)(tile[v_loc][eo + 0] + ba.x);
            h[1] = (_Float16)(tile[v_loc][eo + 1] + ba.y);
            h[2] = (_Float16)(tile[v_loc][eo + 2] + ba.z);
            h[3] = (_Float16)(tile[v_loc][eo + 3] + ba.w);
            h[4] = (_Float16)(tile[v_loc][eo + 4] + bb.x);
            h[5] = (_Float16)(tile[v_loc][eo + 5] + bb.y);
            h[6] = (_Float16)(tile[v_loc][eo + 6] + bb.z);
            h[7] = (_Float16)(tile[v_loc][eo + 7] + bb.w);
            *(f16x8*)&Wt[(size_t)v * EMBED + e0 + eo] = h;
        }
    }
}

// Pass 2: out[token][:] = (float)Wt_h[x[token]][:] — 32 lanes/token,
// f16x4 (8 B) read + ONE packed f32x4 (16 B) store per lane (wave store =
// contiguous 1 KB). 4 independent (token,quad) pairs per thread for MLP.
__global__ void gather_h_kernel(const int* __restrict__ x,
                                const f16x4* __restrict__ Wt,
                                f32x4* __restrict__ out) {
    const int gid    = blockIdx.x * blockDim.x + threadIdx.x;
    const int stride = gridDim.x * blockDim.x;   // multiple of 32

    int g[4], idx[4];
#pragma unroll
    for (int k = 0; k < 4; ++k) {
        g[k]   = gid + k * stride;
        idx[k] = x[g[k] >> 5];                   // broadcast across 32 lanes
    }
    f16x4 h[4];
#pragma unroll
    for (int k = 0; k < 4; ++k)
        h[k] = Wt[(size_t)idx[k] * 32 + (g[k] & 31)];
#pragma unroll
    for (int k = 0; k < 4; ++k) {
        f32x4 r;
        r.x = (float)h[k][0];
        r.y = (float)h[k][1];
        r.z = (float)h[k][2];
        r.w = (float)h[k][3];
        out[g[k]] = r;                           // fully coalesced
    }
}

// Fallback (ws too small): exact fp32 strided column gather.
__global__ void direct_kernel(const int* __restrict__ x,
                              const float* __restrict__ W,
                              const float* __restrict__ bias,
                              f32x4* __restrict__ out) {
    const int gid   = blockIdx.x * blockDim.x + threadIdx.x;
    const int token = gid >> 5;
    const int e4    = gid & 31;
    const int idx   = x[token];
    const int e     = e4 * 4;
    f32x4 r;
    r.x = W[(size_t)(e + 0) * VOCAB + idx] + bias[e + 0];
    r.y = W[(size_t)(e + 1) * VOCAB + idx] + bias[e + 1];
    r.z = W[(size_t)(e + 2) * VOCAB + idx] + bias[e + 2];
    r.w = W[(size_t)(e + 3) * VOCAB + idx] + bias[e + 3];
    out[(size_t)token * 32 + e4] = r;
}

extern "C" void kernel_launch(void* const* d_in, const int* in_sizes, int n_in,
                              void* d_out, int out_size, void* d_ws, size_t ws_size,
                              hipStream_t stream) {
    const int*   x    = (const int*)d_in[0];
    const float* W    = (const float*)d_in[1];
    const float* bias = (const float*)d_in[2];

    const size_t wt_bytes = (size_t)VOCAB * EMBED * sizeof(_Float16); // 12.9 MB

    if (ws_size >= wt_bytes) {
        _Float16* Wt = (_Float16*)d_ws;
        dim3 tgrid((VOCAB + 63) / 64, 2);   // 786 x 2 = 1572 blocks
        transpose_h_kernel<<<tgrid, 256, 0, stream>>>(W, bias, Wt);

        // quads = NTOK*32 = 8,388,608; 4 per thread -> 2,097,152 threads
        const int gblocks = (NTOK * 32 / 4) / 256;   // 8192
        gather_h_kernel<<<gblocks, 256, 0, stream>>>(x, (const f16x4*)Wt,
                                                     (f32x4*)d_out);
    } else {
        const int dblocks = (NTOK * 32) / 256;
        direct_kernel<<<dblocks, 256, 0, stream>>>(x, W, bias, (f32x4*)d_out);
    }
}

// Round 7
// 45.716 us; speedup vs baseline: 1.5389x; 1.0267x over previous
//
#include <hip/hip_runtime.h>

#define VOCAB 50257
#define EMBED 128
#define NTOK  (64 * 4096)
#define NSLICE 8            // 8 slices x 16 embed dims; slice s -> XCD s

typedef float    f32x4 __attribute__((ext_vector_type(4)));
typedef _Float16 f16x4 __attribute__((ext_vector_type(4)));
typedef _Float16 f16x8 __attribute__((ext_vector_type(8)));

// Pass 1: slice-major fp16 table with bias folded:
//   Wt[s][v][e'] = (half)(W[s*16+e'][v] + bias[s*16+e'])
// LDS-tiled transpose, tile 64v x 64e. grid=(786,2), block=256.
__global__ void transpose_h_kernel(const float* __restrict__ W,
                                   const float* __restrict__ bias,
                                   _Float16* __restrict__ Wt) {
    __shared__ float tile[64][65];   // [v_loc][e_loc], +1 pad
    const int t  = threadIdx.x;
    const int v0 = blockIdx.x * 64;
    const int e0 = blockIdx.y * 64;
    const bool full = (v0 + 64 <= VOCAB);

    // Phase 1: load W[e0+e_loc][v0 + 4*(t&15) .. +3] as f32x4 (coalesced in v).
    if (full) {
#pragma unroll
        for (int it = 0; it < 4; ++it) {
            const int e_loc = (t >> 4) + it * 16;
            const int c4    = (t & 15) * 4;
            f32x4 val = *(const f32x4*)&W[(size_t)(e0 + e_loc) * VOCAB + v0 + c4];
            tile[c4 + 0][e_loc] = val.x;
            tile[c4 + 1][e_loc] = val.y;
            tile[c4 + 2][e_loc] = val.z;
            tile[c4 + 3][e_loc] = val.w;
        }
    } else {
        // Tail v-block (v0 = 50240, 17 valid): guarded scalar loads.
#pragma unroll
        for (int it = 0; it < 16; ++it) {
            const int e_loc = (t >> 6) + it * 4;
            const int c     = t & 63;
            const int v     = v0 + c;
            tile[c][e_loc] = (v < VOCAB) ? W[(size_t)(e0 + e_loc) * VOCAB + v]
                                         : 0.0f;
        }
    }
    __syncthreads();

    // Phase 2: write f16x8 into slice-major layout.
    // eg = e0 + (t&7)*8 ; slice = eg>>4 ; e' = eg&15 (0 or 8).
    const int eo = (t & 7) * 8;
    const int eg = e0 + eo;
    const int s  = eg >> 4;
    const int ep = eg & 15;
    const f32x4 ba = *(const f32x4*)&bias[eg];
    const f32x4 bb = *(const f32x4*)&bias[eg + 4];
#pragma unroll
    for (int it = 0; it < 2; ++it) {
        const int v_loc = (t >> 3) + it * 32;
        const int v     = v0 + v_loc;
        if (v < VOCAB) {
            f16x8 h;
            h[0] = (_Float16)(tile[v_loc][eo + 0] + ba.x);
            h[1] = (_Float16)(tile[v_loc][eo + 1] + ba.y);
            h[2] = (_Float16)(tile[v_loc][eo + 2] + ba.z);
            h[3] = (_Float16)(tile[v_loc][eo + 3] + ba.w);
            h[4] = (_Float16)(tile[v_loc][eo + 4] + bb.x);
            h[5] = (_Float16)(tile[v_loc][eo + 5] + bb.y);
            h[6] = (_Float16)(tile[v_loc][eo + 6] + bb.z);
            h[7] = (_Float16)(tile[v_loc][eo + 7] + bb.w);
            *(f16x8*)&Wt[((size_t)s * VOCAB + v) * 16 + ep] = h;
        }
    }
}

// Pass 2: sliced gather. Block bid handles slice (bid & 7) -> lands on XCD
// (bid & 7) under round-robin dispatch, so each XCD's L2 working set is one
// contiguous 1.6 MB table slice + x. 4 lanes per token-slice: f16x4 (8 B)
// L2 read -> f32x4 (16 B) store; each 4-lane group writes one full 64 B line.
__global__ void gather_sliced_kernel(const int* __restrict__ x,
                                     const f16x4* __restrict__ Wt,
                                     f32x4* __restrict__ out) {
    const int bid   = blockIdx.x;
    const int slice = bid & (NSLICE - 1);
    const int tblk  = bid >> 3;
    const int t     = threadIdx.x;
    const int tok   = tblk * 64 + (t >> 2);   // 64 tokens per block
    const int q     = t & 3;                  // f16x4 quad within slice
    const int idx   = x[tok];
    // slice-major: f16x4 element ((slice*VOCAB + idx)*4 + q)
    const f16x4 h = Wt[((size_t)slice * VOCAB + idx) * 4 + q];
    f32x4 r;
    r.x = (float)h[0];
    r.y = (float)h[1];
    r.z = (float)h[2];
    r.w = (float)h[3];
    out[(size_t)tok * 32 + slice * 4 + q] = r;
}

// Fallback (ws too small): exact fp32 strided column gather.
__global__ void direct_kernel(const int* __restrict__ x,
                              const float* __restrict__ W,
                              const float* __restrict__ bias,
                              f32x4* __restrict__ out) {
    const int gid   = blockIdx.x * blockDim.x + threadIdx.x;
    const int token = gid >> 5;
    const int e4    = gid & 31;
    const int idx   = x[token];
    const int e     = e4 * 4;
    f32x4 r;
    r.x = W[(size_t)(e + 0) * VOCAB + idx] + bias[e + 0];
    r.y = W[(size_t)(e + 1) * VOCAB + idx] + bias[e + 1];
    r.z = W[(size_t)(e + 2) * VOCAB + idx] + bias[e + 2];
    r.w = W[(size_t)(e + 3) * VOCAB + idx] + bias[e + 3];
    out[(size_t)token * 32 + e4] = r;
}

extern "C" void kernel_launch(void* const* d_in, const int* in_sizes, int n_in,
                              void* d_out, int out_size, void* d_ws, size_t ws_size,
                              hipStream_t stream) {
    const int*   x    = (const int*)d_in[0];
    const float* W    = (const float*)d_in[1];
    const float* bias = (const float*)d_in[2];

    const size_t wt_bytes = (size_t)VOCAB * EMBED * sizeof(_Float16); // 12.9 MB

    if (ws_size >= wt_bytes) {
        _Float16* Wt = (_Float16*)d_ws;
        dim3 tgrid((VOCAB + 63) / 64, 2);   // 786 x 2 = 1572 blocks
        transpose_h_kernel<<<tgrid, 256, 0, stream>>>(W, bias, Wt);

        // blocks = NTOK/64 token-blocks * 8 slices = 32768 (multiple of 8)
        const int gblocks = (NTOK / 64) * NSLICE;
        gather_sliced_kernel<<<gblocks, 256, 0, stream>>>(x, (const f16x4*)Wt,
                                                          (f32x4*)d_out);
    } else {
        const int dblocks = (NTOK * 32) / 256;
        direct_kernel<<<dblocks, 256, 0, stream>>>(x, W, bias, (f32x4*)d_out);
    }
}